// Round 2
// baseline (428.950 us; speedup 1.0000x reference)
//
#include <hip/hip_runtime.h>
#include <cstdint>

#define D 128
#define T 64
#define B 512
#define EPSF 1e-5f

// ---------------------------------------------------------------------------
// prep: vT[k*D+i] = v[i][k] = W[i][k]/max(norm_i,1e-12); vd[i]=v[i][i]; absb=|b|
// grid 128 blocks x 64 threads; block i handles row i.
// ---------------------------------------------------------------------------
__global__ __launch_bounds__(64) void prep_kernel(const float* __restrict__ W,
                                                  const float* __restrict__ b,
                                                  float* __restrict__ vT,
                                                  float* __restrict__ vd,
                                                  float* __restrict__ absb) {
    const int i = blockIdx.x;
    const int l = threadIdx.x;
    float w0 = W[i * D + l];
    float w1 = W[i * D + l + 64];
    float p = w0 * w0 + w1 * w1;
#pragma unroll
    for (int off = 32; off; off >>= 1) p += __shfl_xor(p, off);
    float norm = sqrtf(p);
    float scale = norm > 1e-12f ? norm : 1e-12f;
    float v0 = w0 / scale;
    float v1 = w1 / scale;
    vT[l * D + i] = v0;
    vT[(l + 64) * D + i] = v1;
    if (i < 64) {
        if (l == i) vd[i] = v0;
    } else {
        if (l == i - 64) vd[i] = v1;
    }
    if (i == 0) {
        absb[l] = fabsf(b[l]);
        absb[l + 64] = fabsf(b[l + 64]);
    }
}

// ---------------------------------------------------------------------------
// main RNN kernel: one wave per batch column, 2 rows per lane (lane, lane+64).
// grid 256 blocks x 128 threads (2 waves = 2 batches per block, sharing vT LDS).
// ---------------------------------------------------------------------------
__global__ __launch_bounds__(128) void rnn_kernel(const float* __restrict__ input,
                                                  const float* __restrict__ target,
                                                  const float* __restrict__ returns,
                                                  const float* __restrict__ vTg,
                                                  const float* __restrict__ vdg,
                                                  const float* __restrict__ absbg,
                                                  float* __restrict__ out) {
    __shared__ float vsh[D * D];   // transposed: vsh[k*D + i] = v[i][k]

    const int tid = threadIdx.x;
    // cooperative load of vT (64 KB), float4-vectorized
    {
        const float4* src = (const float4*)vTg;
        float4* dst = (float4*)vsh;
#pragma unroll
        for (int c = 0; c < 32; ++c) dst[c * 128 + tid] = src[c * 128 + tid];
    }
    __syncthreads();

    const int w = tid >> 6;
    const int lane = tid & 63;
    const int b = blockIdx.x * 2 + w;
    const int rlo = lane, rhi = lane + 64;

    const float tgt_lo = target[rlo], tgt_hi = target[rhi];
    const float a_lo = absbg[rlo], a_hi = absbg[rhi];
    const float aeps_lo = a_lo + EPSF, aeps_hi = a_hi + EPSF;
    const float vd_lo = vdg[rlo], vd_hi = vdg[rhi];

    float h_lo = input[rlo * T * B + b];
    float h_hi = input[rhi * T * B + b];
    out[rlo * T * B + b] = h_lo;
    out[rhi * T * B + b] = h_hi;

    // prefetch r for t=1 (returns[:, 0, :])
    float r_lo = returns[rlo * T * B + b];
    float r_hi = returns[rhi * T * B + b];

    for (int t = 1; t < T; ++t) {
        // ---- adj = h*(1+r)/(1 + sum(h*r)) ----
        float num_lo = h_lo * (1.0f + r_lo);
        float num_hi = h_hi * (1.0f + r_hi);
        float p = h_lo * r_lo + h_hi * r_hi;
#pragma unroll
        for (int off = 32; off; off >>= 1) p += __shfl_xor(p, off);
        float den = 1.0f + p;
        float adj_lo = num_lo / den;
        float adj_hi = num_hi / den;

        // prefetch next step's r early (hidden under the matvec)
        if (t < T - 1) {
            r_lo = returns[rlo * T * B + t * B + b];
            r_hi = returns[rhi * T * B + t * B + b];
        }

        const float x_lo = adj_lo - tgt_lo;
        const float x_hi = adj_hi - tgt_hi;

        // ---- s = v @ (adj - pi_bar) ; conflict-free LDS + readlane bcast ----
        float s_lo = 0.0f, s_hi = 0.0f;
#pragma unroll
        for (int k = 0; k < 64; ++k) {
            float xb = __shfl(x_lo, k);
            s_lo = fmaf(vsh[k * D + rlo], xb, s_lo);
            s_hi = fmaf(vsh[k * D + rhi], xb, s_hi);
        }
#pragma unroll
        for (int k = 0; k < 64; ++k) {
            float xb = __shfl(x_hi, k);
            s_lo = fmaf(vsh[(k + 64) * D + rlo], xb, s_lo);
            s_hi = fmaf(vsh[(k + 64) * D + rhi], xb, s_hi);
        }

        h_lo = adj_lo;
        h_hi = adj_hi;

        // ---- judge ----
        bool in_lo = (s_lo < aeps_lo) && (s_lo > -aeps_lo);
        bool in_hi = (s_hi < aeps_hi) && (s_hi > -aeps_hi);
        uint64_t q0b = __ballot(in_lo && in_hi);
        bool viol_lo = (s_lo > a_lo) || (s_lo < -a_lo);
        bool viol_hi = (s_hi > a_hi) || (s_hi < -a_hi);
        uint64_t mlo = __ballot(viol_lo);
        uint64_t mhi = __ballot(viol_hi);

        // q0 shortcut valid only if some zero-delta column exists
        bool judge = (q0b == ~0ull) && ((mlo != ~0ull) || (mhi != ~0ull));

        if (!judge) {
            // initial delta (from original s), division to match reference
            float dl = 0.0f, dh = 0.0f;
            if (s_lo > a_lo) dl = (a_lo - s_lo) / vd_lo;
            else if (s_lo < -a_lo) dl = (-a_lo - s_lo) / vd_lo;
            if (s_hi > a_hi) dh = (a_hi - s_hi) / vd_hi;
            else if (s_hi < -a_hi) dh = (-a_hi - s_hi) / vd_hi;

            uint64_t t_mlo = mlo, t_mhi = mhi;
            while (t_mlo | t_mhi) {
                int j;
                float dj;
                if (t_mlo) {
                    int jl = (int)__ffsll((unsigned long long)t_mlo) - 1;
                    t_mlo &= t_mlo - 1;
                    j = jl;
                    dj = __shfl(dl, jl);
                } else {
                    int jh = (int)__ffsll((unsigned long long)t_mhi) - 1;
                    t_mhi &= t_mhi - 1;
                    j = 64 + jh;
                    dj = __shfl(dh, jh);
                }
                float n_lo = fmaf(vsh[j * D + rlo], dj, s_lo);
                float n_hi = fmaf(vsh[j * D + rhi], dj, s_hi);
                bool pl = (n_lo < aeps_lo) && (n_lo > -aeps_lo);
                bool ph = (n_hi < aeps_hi) && (n_hi > -aeps_hi);
                if (__ballot(pl && ph) == ~0ull) { judge = true; break; }
            }
        }

        if (judge) {
            // ---- sequential Gauss-Seidel sweep, skipping zero-delta rows ----
            uint64_t rem_lo = ~0ull, rem_hi = ~0ull;
            while (true) {
                uint64_t m1 = __ballot((s_lo > a_lo) || (s_lo < -a_lo)) & rem_lo;
                uint64_t m2 = __ballot((s_hi > a_hi) || (s_hi < -a_hi)) & rem_hi;
                int j;
                if (m1) {
                    int jl = (int)__ffsll((unsigned long long)m1) - 1;
                    j = jl;
                    rem_lo = (jl == 63) ? 0ull : (~0ull << (jl + 1));
                } else if (m2) {
                    int jh = (int)__ffsll((unsigned long long)m2) - 1;
                    j = 64 + jh;
                    rem_lo = 0ull;
                    rem_hi = (jh == 63) ? 0ull : (~0ull << (jh + 1));
                } else {
                    break;
                }
                float dl2 = (s_lo > a_lo) ? (a_lo - s_lo) / vd_lo
                           : ((s_lo < -a_lo) ? (-a_lo - s_lo) / vd_lo : 0.0f);
                float dh2 = (s_hi > a_hi) ? (a_hi - s_hi) / vd_hi
                           : ((s_hi < -a_hi) ? (-a_hi - s_hi) / vd_hi : 0.0f);
                float dj = __shfl((j < 64) ? dl2 : dh2, j & 63);
                if (lane == (j & 63)) {
                    if (j < 64) h_lo += dj; else h_hi += dj;
                }
                s_lo = fmaf(vsh[j * D + rlo], dj, s_lo);
                s_hi = fmaf(vsh[j * D + rhi], dj, s_hi);
            }
        } else {
            // ---- bisection between pi_bar (s=0) and adj (s), in s-space ----
            float hin_lo = tgt_lo, hin_hi = tgt_hi;
            float sin_lo = 0.0f, sin_hi = 0.0f;
            float hout_lo = h_lo, hout_hi = h_hi;
            float sout_lo = s_lo, sout_hi = s_hi;
            float hm_lo = 0.0f, hm_hi = 0.0f;
#pragma unroll
            for (int it = 0; it < 10; ++it) {
                hm_lo = hin_lo + (hout_lo - hin_lo) * 0.5f;
                hm_hi = hin_hi + (hout_hi - hin_hi) * 0.5f;
                float sm_lo = sin_lo + (sout_lo - sin_lo) * 0.5f;
                float sm_hi = sin_hi + (sout_hi - sin_hi) * 0.5f;
                bool pl = (sm_lo <= aeps_lo) && (sm_lo >= -aeps_lo);
                bool ph = (sm_hi <= aeps_hi) && (sm_hi >= -aeps_hi);
                bool inside = (__ballot(pl && ph) == ~0ull);
                if (inside) {
                    hin_lo = hm_lo; hin_hi = hm_hi;
                    sin_lo = sm_lo; sin_hi = sm_hi;
                } else {
                    hout_lo = hm_lo; hout_hi = hm_hi;
                    sout_lo = sm_lo; sout_hi = sm_hi;
                }
            }
            h_lo = hm_lo;
            h_hi = hm_hi;
        }

        out[rlo * T * B + t * B + b] = h_lo;
        out[rhi * T * B + t * B + b] = h_hi;
    }

    // h_last (D,1,B)
    out[D * T * B + rlo * B + b] = h_lo;
    out[D * T * B + rhi * B + b] = h_hi;
}

extern "C" void kernel_launch(void* const* d_in, const int* in_sizes, int n_in,
                              void* d_out, int out_size, void* d_ws, size_t ws_size,
                              hipStream_t stream) {
    const float* input   = (const float*)d_in[0];
    const float* target  = (const float*)d_in[1];
    const float* returns = (const float*)d_in[2];
    // d_in[3] = hidden (unused by the reference)
    const float* W = (const float*)d_in[4];
    const float* b = (const float*)d_in[5];
    float* out = (float*)d_out;

    float* vT   = (float*)d_ws;            // 16384 floats
    float* vd   = vT + D * D;              // 128 floats
    float* absb = vd + D;                  // 128 floats

    prep_kernel<<<D, 64, 0, stream>>>(W, b, vT, vd, absb);
    rnn_kernel<<<B / 2, 128, 0, stream>>>(input, target, returns, vT, vd, absb, out);
}

// Round 3
// 217.641 us; speedup vs baseline: 1.9709x; 1.9709x over previous
//
#include <hip/hip_runtime.h>
#include <cstdint>

#define D 128
#define T 64
#define B 512
#define EPSF 1e-5f

// wave-uniform lane broadcast via v_readlane (no LDS/ds_bpermute)
__device__ __forceinline__ float lane_bcast(float x, int l) {
    return __int_as_float(__builtin_amdgcn_readlane(__float_as_int(x), l));
}

// ---------------------------------------------------------------------------
// prep: vT[k*D+i] = v[i][k] = W[i][k]/max(norm_i,1e-12); vd[i]=v[i][i]; absb=|b|
// ---------------------------------------------------------------------------
__global__ __launch_bounds__(64) void prep_kernel(const float* __restrict__ W,
                                                  const float* __restrict__ b,
                                                  float* __restrict__ vT,
                                                  float* __restrict__ vd,
                                                  float* __restrict__ absb) {
    const int i = blockIdx.x;
    const int l = threadIdx.x;
    float w0 = W[i * D + l];
    float w1 = W[i * D + l + 64];
    float p = w0 * w0 + w1 * w1;
#pragma unroll
    for (int off = 32; off; off >>= 1) p += __shfl_xor(p, off);
    float norm = sqrtf(p);
    float scale = norm > 1e-12f ? norm : 1e-12f;
    float v0 = w0 / scale;
    float v1 = w1 / scale;
    vT[l * D + i] = v0;
    vT[(l + 64) * D + i] = v1;
    if (i < 64) {
        if (l == i) vd[i] = v0;
    } else {
        if (l == i - 64) vd[i] = v1;
    }
    if (i == 0) {
        absb[l] = fabsf(b[l]);
        absb[l + 64] = fabsf(b[l + 64]);
    }
}

// ---------------------------------------------------------------------------
// main RNN kernel. One wave per batch column; lane owns rows (lane, lane+64).
// v stored swizzled in LDS: v[i][k] at vsh[k*128 + (i ^ ((k&7)<<2))].
//  - row reads (matvec/sweep; fixed k, i=lane): 2-way bank alias = free
//  - column reads (parallel judge; fixed j=lane, i contiguous x4): b128,
//    8 requests/bank = structural minimum
// ---------------------------------------------------------------------------
__global__ __launch_bounds__(128) void rnn_kernel(const float* __restrict__ input,
                                                  const float* __restrict__ target,
                                                  const float* __restrict__ returns,
                                                  const float* __restrict__ vTg,
                                                  const float* __restrict__ vdg,
                                                  const float* __restrict__ absbg,
                                                  float* __restrict__ out) {
    __shared__ float vsh[D * D];   // exactly 64 KB

    const int tid = threadIdx.x;
    // cooperative swizzled load of vT (plain layout in ws -> swizzled LDS)
    {
        const float4* src = (const float4*)vTg;
        float4* dst = (float4*)vsh;
#pragma unroll
        for (int c = 0; c < 32; ++c) {
            int f = c * 128 + tid;          // source float4 index
            int k = f >> 5;                 // row k of vT
            int i = (f & 31) << 2;          // starting i of this float4
            int ck = (k & 7) << 2;
            int d4 = k * 32 + (((i ^ ck)) >> 2);
            dst[d4] = src[f];
        }
    }
    __syncthreads();

    const int w = tid >> 6;
    const int lane = tid & 63;
    const int b = blockIdx.x * 2 + w;
    const int rlo = lane, rhi = lane + 64;

    const float tgt_lo = target[rlo], tgt_hi = target[rhi];
    const float a_lo = absbg[rlo], a_hi = absbg[rhi];
    const float aeps_lo = a_lo + EPSF, aeps_hi = a_hi + EPSF;
    const float vd_lo = vdg[rlo], vd_hi = vdg[rhi];
    const float rvd_lo = 1.0f / vd_lo, rvd_hi = 1.0f / vd_hi;

    // matvec/sweep row-read xor bases: vsh[k*128 + ax[k&7]] (+64 for hi row)
    int ax[8];
#pragma unroll
    for (int c = 0; c < 8; ++c) ax[c] = rlo ^ (c << 2);

    // parallel-judge column bases: candidate j=lane reads float4 at
    // Abase[c] + 32*a  (logical i0 = a*32 + c*4); candidate lane+64 at +8192
    const int cj = (lane & 7) << 2;
    int Abase[8];
#pragma unroll
    for (int c = 0; c < 8; ++c) Abase[c] = lane * 128 + ((c << 2) ^ cj);

    float h_lo = input[rlo * T * B + b];
    float h_hi = input[rhi * T * B + b];
    out[rlo * T * B + b] = h_lo;
    out[rhi * T * B + b] = h_hi;

    float r_lo = returns[rlo * T * B + b];
    float r_hi = returns[rhi * T * B + b];

    for (int t = 1; t < T; ++t) {
        // ---- adj = h*(1+r)/(1 + sum(h*r)) ----
        float num_lo = h_lo * (1.0f + r_lo);
        float num_hi = h_hi * (1.0f + r_hi);
        float p = h_lo * r_lo + h_hi * r_hi;
#pragma unroll
        for (int off = 32; off; off >>= 1) p += __shfl_xor(p, off);
        float den = 1.0f + p;
        float adj_lo = num_lo / den;
        float adj_hi = num_hi / den;

        if (t < T - 1) {
            r_lo = returns[rlo * T * B + t * B + b];
            r_hi = returns[rhi * T * B + t * B + b];
        }

        const float x_lo = adj_lo - tgt_lo;
        const float x_hi = adj_hi - tgt_hi;

        // ---- s = v @ (adj - pi_bar); readlane broadcast + swizzled LDS ----
        float s_lo = 0.0f, s_hi = 0.0f;
#pragma unroll
        for (int k = 0; k < 64; ++k) {
            float xb = lane_bcast(x_lo, k);
            s_lo = fmaf(vsh[k * 128 + ax[k & 7]], xb, s_lo);
            s_hi = fmaf(vsh[k * 128 + ax[k & 7] + 64], xb, s_hi);
        }
#pragma unroll
        for (int k = 0; k < 64; ++k) {
            float xb = lane_bcast(x_hi, k);
            s_lo = fmaf(vsh[(k + 64) * 128 + ax[k & 7]], xb, s_lo);
            s_hi = fmaf(vsh[(k + 64) * 128 + ax[k & 7] + 64], xb, s_hi);
        }

        h_lo = adj_lo;
        h_hi = adj_hi;

        bool viol_lo = (s_lo > a_lo) || (s_lo < -a_lo);
        bool viol_hi = (s_hi > a_hi) || (s_hi < -a_hi);
        uint64_t mlo = __ballot(viol_lo);
        uint64_t mhi = __ballot(viol_hi);

        if ((mlo | mhi) != 0ull) {
            // per-lane deltas (reference lam formulas, IEEE div)
            float dl = 0.0f, dh = 0.0f;
            if (s_lo > a_lo) dl = (a_lo - s_lo) / vd_lo;
            else if (s_lo < -a_lo) dl = (-a_lo - s_lo) / vd_lo;
            if (s_hi > a_hi) dh = (a_hi - s_hi) / vd_hi;
            else if (s_hi < -a_hi) dh = (-a_hi - s_hi) / vd_hi;

            int V = __popcll(mlo) + __popcll(mhi);
            bool judge;

            if (V <= 8) {
                // q0: all strictly inside a+eps and (V<64 so) a zero-delta
                // column exists
                bool in_lo = (s_lo < aeps_lo) && (s_lo > -aeps_lo);
                bool in_hi = (s_hi < aeps_hi) && (s_hi > -aeps_hi);
                judge = (__ballot(in_lo && in_hi) == ~0ull);
                if (!judge) {
                    uint64_t t_mlo = mlo, t_mhi = mhi;
                    while (t_mlo | t_mhi) {
                        int j;
                        float dj;
                        if (t_mlo) {
                            int jl = (int)__ffsll((unsigned long long)t_mlo) - 1;
                            t_mlo &= t_mlo - 1;
                            j = jl;
                            dj = lane_bcast(dl, jl);
                        } else {
                            int jh = (int)__ffsll((unsigned long long)t_mhi) - 1;
                            t_mhi &= t_mhi - 1;
                            j = 64 + jh;
                            dj = lane_bcast(dh, jh);
                        }
                        int cjj = (j & 7) << 2;
                        int base = j * 128 + (rlo ^ cjj);
                        float n_lo = fmaf(vsh[base], dj, s_lo);
                        float n_hi = fmaf(vsh[base + 64], dj, s_hi);
                        bool pl = (n_lo < aeps_lo) && (n_lo > -aeps_lo);
                        bool ph = (n_hi < aeps_hi) && (n_hi > -aeps_hi);
                        if (__ballot(pl && ph) == ~0ull) { judge = true; break; }
                    }
                }
            } else {
                // ---- parallel judge: lane tests candidates j=lane, lane+64.
                // Covers d=0 candidates (q0) uniformly.
                float m1 = -1.0f, m2 = -1.0f;   // only the sign of max matters
#pragma unroll
                for (int a = 0; a < 4; ++a) {
#pragma unroll
                    for (int c = 0; c < 8; ++c) {
                        const int i0 = a * 32 + c * 4;
                        const float* p1 = &vsh[Abase[c] + 32 * a];
                        float4 c1 = *(const float4*)p1;
                        float4 c2 = *(const float4*)(p1 + 8192);
#pragma unroll
                        for (int e = 0; e < 4; ++e) {
                            const int i = i0 + e;
                            float sv = (i < 64) ? lane_bcast(s_lo, i)
                                                : lane_bcast(s_hi, i - 64);
                            float ae = (i < 64) ? lane_bcast(aeps_lo, i)
                                                : lane_bcast(aeps_hi, i - 64);
                            float f1 = ((const float*)&c1)[e];
                            float f2 = ((const float*)&c2)[e];
                            m1 = fmaxf(m1, fabsf(fmaf(f1, dl, sv)) - ae);
                            m2 = fmaxf(m2, fabsf(fmaf(f2, dh, sv)) - ae);
                        }
                    }
                }
                judge = ((__ballot(m1 < 0.0f) | __ballot(m2 < 0.0f)) != 0ull);
            }

            if (judge) {
                // ---- Gauss-Seidel sweep (ascending j, violators only) ----
                uint64_t rem_lo = ~0ull, rem_hi = ~0ull;
                while (true) {
                    uint64_t m1b = __ballot((s_lo > a_lo) || (s_lo < -a_lo)) & rem_lo;
                    uint64_t m2b = __ballot((s_hi > a_hi) || (s_hi < -a_hi)) & rem_hi;
                    int j;
                    if (m1b) {
                        int jl = (int)__ffsll((unsigned long long)m1b) - 1;
                        j = jl;
                        rem_lo = (jl == 63) ? 0ull : (~0ull << (jl + 1));
                    } else if (m2b) {
                        int jh = (int)__ffsll((unsigned long long)m2b) - 1;
                        j = 64 + jh;
                        rem_lo = 0ull;
                        rem_hi = (jh == 63) ? 0ull : (~0ull << (jh + 1));
                    } else {
                        break;
                    }
                    float dl2 = (s_lo > a_lo) ? (a_lo - s_lo) * rvd_lo
                               : ((s_lo < -a_lo) ? (-a_lo - s_lo) * rvd_lo : 0.0f);
                    float dh2 = (s_hi > a_hi) ? (a_hi - s_hi) * rvd_hi
                               : ((s_hi < -a_hi) ? (-a_hi - s_hi) * rvd_hi : 0.0f);
                    float srcv = (j < 64) ? dl2 : dh2;
                    float dj = lane_bcast(srcv, j & 63);
                    if (lane == (j & 63)) {
                        if (j < 64) h_lo += dj; else h_hi += dj;
                    }
                    int cjj = (j & 7) << 2;
                    int base = j * 128 + (rlo ^ cjj);
                    s_lo = fmaf(vsh[base], dj, s_lo);
                    s_hi = fmaf(vsh[base + 64], dj, s_hi);
                }
            } else {
                // ---- bisection between pi_bar (s=0) and adj (s), s-space ----
                float hin_lo = tgt_lo, hin_hi = tgt_hi;
                float sin_lo = 0.0f, sin_hi = 0.0f;
                float hout_lo = h_lo, hout_hi = h_hi;
                float sout_lo = s_lo, sout_hi = s_hi;
                float hm_lo = 0.0f, hm_hi = 0.0f;
#pragma unroll
                for (int it = 0; it < 10; ++it) {
                    hm_lo = hin_lo + (hout_lo - hin_lo) * 0.5f;
                    hm_hi = hin_hi + (hout_hi - hin_hi) * 0.5f;
                    float sm_lo = sin_lo + (sout_lo - sin_lo) * 0.5f;
                    float sm_hi = sin_hi + (sout_hi - sin_hi) * 0.5f;
                    bool pl = (sm_lo <= aeps_lo) && (sm_lo >= -aeps_lo);
                    bool ph = (sm_hi <= aeps_hi) && (sm_hi >= -aeps_hi);
                    bool inside = (__ballot(pl && ph) == ~0ull);
                    if (inside) {
                        hin_lo = hm_lo; hin_hi = hm_hi;
                        sin_lo = sm_lo; sin_hi = sm_hi;
                    } else {
                        hout_lo = hm_lo; hout_hi = hm_hi;
                        sout_lo = sm_lo; sout_hi = sm_hi;
                    }
                }
                h_lo = hm_lo;
                h_hi = hm_hi;
            }
        }
        // else: no violators -> judge=1, sweep is a no-op, h unchanged

        out[rlo * T * B + t * B + b] = h_lo;
        out[rhi * T * B + t * B + b] = h_hi;
    }

    out[D * T * B + rlo * B + b] = h_lo;
    out[D * T * B + rhi * B + b] = h_hi;
}

extern "C" void kernel_launch(void* const* d_in, const int* in_sizes, int n_in,
                              void* d_out, int out_size, void* d_ws, size_t ws_size,
                              hipStream_t stream) {
    const float* input   = (const float*)d_in[0];
    const float* target  = (const float*)d_in[1];
    const float* returns = (const float*)d_in[2];
    // d_in[3] = hidden (unused by the reference)
    const float* W = (const float*)d_in[4];
    const float* b = (const float*)d_in[5];
    float* out = (float*)d_out;

    float* vT   = (float*)d_ws;            // 16384 floats
    float* vd   = vT + D * D;              // 128 floats
    float* absb = vd + D;                  // 128 floats

    prep_kernel<<<D, 64, 0, stream>>>(W, b, vT, vd, absb);
    rnn_kernel<<<B / 2, 128, 0, stream>>>(input, target, returns, vT, vd, absb, out);
}